// Round 1
// baseline (1778.511 us; speedup 1.0000x reference)
//
#include <hip/hip_runtime.h>
#include <hip/hip_bf16.h>

// Shapes: B=512, S=128, D=128, HS=256, 4HS=1024, O=1.
// Pipeline (all bf16 MFMA, f32 accum):
//   prepw: WaT/VaT/WT transposed bf16 weights + U packed into MFMA B-fragment order
//   preph: H -> bf16 copy + per-b transpose HT[b][d][s]
//   k_att1: T1 = tanh(H @ Wa + ba)            [65536 x 128]
//   k_att2: beta = softmax(T1 @ Va)           [65536 x 128]
//   k_pool: poolT[t*512+b][d] = beta[b] @ H[b]   (transposed M so k_gx tiles = seq groups)
//   k_gx:   Gx = pool @ W + bias, stored packed [g][t][w][tt][lane][4] bf16
//   k_seq:  32 blocks x 16 batch rows, 128-step LSTM; U: 3 K-chunks in VGPRs + 5 streamed from L2

using bf16x8 = __attribute__((ext_vector_type(8))) short;
using f32x4  = __attribute__((ext_vector_type(4))) float;

#define DEV static __device__ __forceinline__

DEV unsigned short f2bf(float x) {
    unsigned u = __float_as_uint(x);
    u += 0x7fffu + ((u >> 16) & 1u);          // round-to-nearest-even
    return (unsigned short)(u >> 16);
}
DEV float bf2f(unsigned short s) { return __uint_as_float(((unsigned)s) << 16); }
DEV float sigm(float x) { return 1.0f / (1.0f + __expf(-x)); }
DEV float tanh_f(float x) { float e = __expf(2.0f * x); return 1.0f - 2.0f / (e + 1.0f); }
DEV f32x4 mfma16(bf16x8 a, bf16x8 b, f32x4 c) {
    return __builtin_amdgcn_mfma_f32_16x16x32_bf16(a, b, c, 0, 0, 0);
}
DEV float gxel(ushort4 v, int j) {
    unsigned short s = (j == 0) ? v.x : (j == 1) ? v.y : (j == 2) ? v.z : v.w;
    return bf2f(s);
}

// stage rows x 128 bf16 (row stride 128) into LDS with padded stride 136 (16B-aligned rows)
DEV void stage128(const unsigned short* __restrict__ src, unsigned short* dst, int rows, int tid) {
    int chunks = rows * 16;
    for (int i = tid; i < chunks; i += 256) {
        int r = i >> 4, c = (i & 15) << 3;
        *(bf16x8*)(dst + r * 136 + c) = *(const bf16x8*)(src + r * 128 + c);
    }
}

// ---------------- prep kernels ----------------
__global__ void k_prepw(const float* __restrict__ Wa, const float* __restrict__ Va,
                        const float* __restrict__ W, const float* __restrict__ U,
                        unsigned short* __restrict__ WaT, unsigned short* __restrict__ VaT,
                        unsigned short* __restrict__ WT, unsigned short* __restrict__ Upk) {
    int idx = blockIdx.x * 256 + threadIdx.x;
    if (idx < 16384) {
        int n = idx >> 7, k = idx & 127;
        WaT[idx] = f2bf(Wa[k * 128 + n]);
    } else if (idx < 32768) {
        int i = idx - 16384;
        int n = i >> 7, k = i & 127;
        VaT[i] = f2bf(Va[k * 128 + n]);
    } else if (idx < 163840) {
        int i = idx - 32768;
        int n = i >> 7, k = i & 127;
        WT[i] = f2bf(W[k * 1024 + n]);
    } else if (idx < 425984) {
        int i = idx - 163840;   // layout: ((((w*8+kc)*8+tt)*64+l)*8+j
        int j = i & 7, ll = (i >> 3) & 63, tt = (i >> 9) & 7, kc = (i >> 12) & 7, w = i >> 15;
        int k = kc * 32 + (ll >> 4) * 8 + j;
        int n = (tt >> 1) * 256 + w * 32 + (tt & 1) * 16 + (ll & 15);
        Upk[i] = f2bf(U[k * 1024 + n]);
    }
}

__global__ void k_preph(const float* __restrict__ H, unsigned short* __restrict__ Hbf,
                        unsigned short* __restrict__ HT) {
    for (size_t idx = (size_t)blockIdx.x * 256 + threadIdx.x; idx < 16777216u;
         idx += (size_t)gridDim.x * 256) {
        if (idx < 8388608u) {
            Hbf[idx] = f2bf(H[idx]);
        } else {
            size_t i = idx - 8388608u;
            int b = (int)(i >> 14);
            int rem = (int)(i & 16383);
            int d = rem >> 7, s = rem & 127;
            HT[i] = f2bf(H[((size_t)b * 128 + s) * 128 + d]);
        }
    }
}

// ---------------- T1 = tanh(H @ Wa + ba) ----------------
__global__ __launch_bounds__(256) void k_att1(const unsigned short* __restrict__ Hbf,
                                              const unsigned short* __restrict__ WaT,
                                              const float* __restrict__ ba,
                                              unsigned short* __restrict__ T1) {
    __shared__ unsigned short a_lds[64 * 136];
    __shared__ unsigned short b_lds[128 * 136];
    int tid = threadIdx.x;
    int m0 = blockIdx.x * 64;
    stage128(Hbf + (size_t)m0 * 128, a_lds, 64, tid);
    stage128(WaT, b_lds, 128, tid);
    __syncthreads();
    int w = tid >> 6, l = tid & 63, q = l >> 4, r = l & 15;
    f32x4 acc[8] = {};
    #pragma unroll
    for (int kc = 0; kc < 4; ++kc) {
        bf16x8 a = *(const bf16x8*)(a_lds + (w * 16 + r) * 136 + kc * 32 + q * 8);
        #pragma unroll
        for (int nt = 0; nt < 8; ++nt) {
            bf16x8 b = *(const bf16x8*)(b_lds + (nt * 16 + r) * 136 + kc * 32 + q * 8);
            acc[nt] = mfma16(a, b, acc[nt]);
        }
    }
    #pragma unroll
    for (int nt = 0; nt < 8; ++nt) {
        int col = nt * 16 + r;
        float bav = ba[col];
        #pragma unroll
        for (int j = 0; j < 4; ++j) {
            int row = m0 + w * 16 + q * 4 + j;
            T1[(size_t)row * 128 + col] = f2bf(tanh_f(acc[nt][j] + bav));
        }
    }
}

// ---------------- beta = softmax(T1 @ Va) ----------------
__global__ __launch_bounds__(256) void k_att2(const unsigned short* __restrict__ T1,
                                              const unsigned short* __restrict__ VaT,
                                              unsigned short* __restrict__ beta) {
    __shared__ __align__(16) char smem[52224];
    unsigned short* a_lds = (unsigned short*)smem;            // 64*136*2 = 17408
    unsigned short* b_lds = (unsigned short*)(smem + 17408);  // 128*136*2 = 34816
    float* lg  = (float*)smem;                                // 64 x 133 (reused after barrier)
    float* inv = (float*)(smem + 34048);                      // 64 floats
    int tid = threadIdx.x;
    int m0 = blockIdx.x * 64;
    stage128(T1 + (size_t)m0 * 128, a_lds, 64, tid);
    stage128(VaT, b_lds, 128, tid);
    __syncthreads();
    int w = tid >> 6, l = tid & 63, q = l >> 4, r = l & 15;
    f32x4 acc[8] = {};
    #pragma unroll
    for (int kc = 0; kc < 4; ++kc) {
        bf16x8 a = *(const bf16x8*)(a_lds + (w * 16 + r) * 136 + kc * 32 + q * 8);
        #pragma unroll
        for (int nt = 0; nt < 8; ++nt) {
            bf16x8 b = *(const bf16x8*)(b_lds + (nt * 16 + r) * 136 + kc * 32 + q * 8);
            acc[nt] = mfma16(a, b, acc[nt]);
        }
    }
    __syncthreads();   // a/b LDS dead; reuse as logits buffer
    #pragma unroll
    for (int nt = 0; nt < 8; ++nt)
        #pragma unroll
        for (int j = 0; j < 4; ++j)
            lg[(w * 16 + q * 4 + j) * 133 + nt * 16 + r] = acc[nt][j];
    __syncthreads();
    if (tid < 64) {
        float mx = -1e30f;
        for (int c = 0; c < 128; ++c) mx = fmaxf(mx, lg[tid * 133 + c]);
        float s = 0.f;
        for (int c = 0; c < 128; ++c) {
            float e = __expf(lg[tid * 133 + c] - mx);
            lg[tid * 133 + c] = e;
            s += e;
        }
        inv[tid] = 1.0f / s;
    }
    __syncthreads();
    for (int i = tid; i < 64 * 128; i += 256) {
        int rr = i >> 7, cc = i & 127;
        beta[(size_t)(m0 + rr) * 128 + cc] = f2bf(lg[rr * 133 + cc] * inv[rr]);
    }
}

// ---------------- poolT[t*512+b][d] = beta[b] @ H[b] ----------------
__global__ __launch_bounds__(256) void k_pool(const unsigned short* __restrict__ beta,
                                              const unsigned short* __restrict__ HT,
                                              unsigned short* __restrict__ poolT) {
    __shared__ unsigned short a_lds[64 * 136];
    __shared__ unsigned short b_lds[128 * 136];
    int tid = threadIdx.x;
    int b = blockIdx.x >> 1, mh = blockIdx.x & 1;
    stage128(beta + ((size_t)b * 128 + mh * 64) * 128, a_lds, 64, tid);
    stage128(HT + (size_t)b * 16384, b_lds, 128, tid);
    __syncthreads();
    int w = tid >> 6, l = tid & 63, q = l >> 4, r = l & 15;
    f32x4 acc[8] = {};
    #pragma unroll
    for (int kc = 0; kc < 4; ++kc) {
        bf16x8 a = *(const bf16x8*)(a_lds + (w * 16 + r) * 136 + kc * 32 + q * 8);
        #pragma unroll
        for (int nt = 0; nt < 8; ++nt) {
            bf16x8 bb = *(const bf16x8*)(b_lds + (nt * 16 + r) * 136 + kc * 32 + q * 8);
            acc[nt] = mfma16(a, bb, acc[nt]);
        }
    }
    #pragma unroll
    for (int nt = 0; nt < 8; ++nt)
        #pragma unroll
        for (int j = 0; j < 4; ++j) {
            int t = mh * 64 + w * 16 + q * 4 + j;
            poolT[((size_t)t * 512 + b) * 128 + nt * 16 + r] = f2bf(acc[nt][j]);
        }
}

// ---------------- Gx = pool @ W + bias, packed in seq fragment order ----------------
__global__ __launch_bounds__(256) void k_gx(const unsigned short* __restrict__ poolT,
                                            const unsigned short* __restrict__ WT,
                                            const float* __restrict__ bias,
                                            unsigned short* __restrict__ Gxp) {
    __shared__ unsigned short a_lds[64 * 136];
    __shared__ unsigned short b_lds[128 * 136];
    int tid = threadIdx.x;
    int mblk = blockIdx.x >> 3, nb = blockIdx.x & 7;
    int t = mblk >> 3, gblk = mblk & 7;
    int m0 = mblk * 64, n0 = nb * 128;
    stage128(poolT + (size_t)m0 * 128, a_lds, 64, tid);
    stage128(WT + (size_t)n0 * 128, b_lds, 128, tid);
    __syncthreads();
    int w = tid >> 6, l = tid & 63, q = l >> 4, r = l & 15;
    f32x4 acc[8] = {};
    #pragma unroll
    for (int kc = 0; kc < 4; ++kc) {
        bf16x8 a = *(const bf16x8*)(a_lds + (w * 16 + r) * 136 + kc * 32 + q * 8);
        #pragma unroll
        for (int nt = 0; nt < 8; ++nt) {
            bf16x8 bb = *(const bf16x8*)(b_lds + (nt * 16 + r) * 136 + kc * 32 + q * 8);
            acc[nt] = mfma16(a, bb, acc[nt]);
        }
    }
    int g_seq = gblk * 4 + w;   // wave's 16 rows = one sequential batch group
    #pragma unroll
    for (int nt = 0; nt < 8; ++nt) {
        int col0 = n0 + nt * 16;
        float bv = bias[col0 + r];
        int w_seq = (col0 & 255) >> 5;
        int tts = ((col0 >> 8) << 1) | ((col0 >> 4) & 1);
        size_t idx4 = ((((size_t)g_seq * 128 + t) * 8 + w_seq) * 8 + tts) * 64 + l;
        ushort4 o;
        o.x = f2bf(acc[nt][0] + bv);
        o.y = f2bf(acc[nt][1] + bv);
        o.z = f2bf(acc[nt][2] + bv);
        o.w = f2bf(acc[nt][3] + bv);
        *(ushort4*)(Gxp + idx4 * 4) = o;   // lane-contiguous: 512B/store-instr
    }
}

// ---------------- sequential LSTM: 32 blocks x 16 batch rows ----------------
__global__ __launch_bounds__(512, 2) void k_seq(const unsigned short* __restrict__ Gxp,
                                                const unsigned short* __restrict__ Upk,
                                                const float* __restrict__ Wy,
                                                const float* __restrict__ fcW,
                                                const float* __restrict__ fcb,
                                                const float* __restrict__ y0,
                                                float* __restrict__ out) {
    __shared__ unsigned short h_lds[2][16][264];  // bf16 h, padded stride (2-way bank alias only)
    __shared__ float ypart[2][8][16];
    int tid = threadIdx.x;
    int g = blockIdx.x;
    int w = tid >> 6, l = tid & 63, q = l >> 4, r = l & 15;
    float fc_b0 = fcb[0];

    // resident U fragments: kc 0..2 (K 0..96) -> 96 VGPRs/thread
    bf16x8 u_res[3][8];
    #pragma unroll
    for (int kc = 0; kc < 3; ++kc)
        #pragma unroll
        for (int tt = 0; tt < 8; ++tt)
            u_res[kc][tt] = *(const bf16x8*)(Upk + (size_t)(((w * 8 + kc) * 8 + tt) * 64 + l) * 8);

    float wy_r[8], fw[2];
    #pragma unroll
    for (int tt = 0; tt < 8; ++tt)
        wy_r[tt] = Wy[(tt >> 1) * 256 + w * 32 + (tt & 1) * 16 + r];
    fw[0] = fcW[w * 32 + r];
    fw[1] = fcW[w * 32 + 16 + r];
    float c_st[2][4] = {};

    for (int i = tid; i < 16 * 264; i += 512) (&h_lds[0][0][0])[i] = 0;
    if (tid < 128) {
        int ww = tid >> 4, rw = tid & 15;
        ypart[0][ww][rw] = (ww == 0) ? (y0[g * 16 + rw] - fc_b0) : 0.0f;
    }
    __syncthreads();

    float* outh = out + 512;
    for (int t = 0; t < 128; ++t) {
        int p = t & 1, np = p ^ 1;
        float yp[4];
        #pragma unroll
        for (int j = 0; j < 4; ++j) {
            float s = fc_b0;
            #pragma unroll
            for (int ww = 0; ww < 8; ++ww) s += ypart[p][ww][q * 4 + j];
            yp[j] = s;
        }
        // Gx loads issued early; consumed in the cell phase (latency hidden behind MFMA)
        ushort4 gx[8];
        {
            size_t base = (((size_t)(g * 128 + t) * 8 + w) * 8) * 64 + l;
            const ushort4* gq = (const ushort4*)Gxp;
            #pragma unroll
            for (int tt = 0; tt < 8; ++tt) gx[tt] = gq[base + (size_t)tt * 64];
        }
        f32x4 acc[8];
        #pragma unroll
        for (int tt = 0; tt < 8; ++tt) {
            acc[tt][0] = yp[0] * wy_r[tt];
            acc[tt][1] = yp[1] * wy_r[tt];
            acc[tt][2] = yp[2] * wy_r[tt];
            acc[tt][3] = yp[3] * wy_r[tt];
        }
        #pragma unroll
        for (int kc = 0; kc < 3; ++kc) {
            bf16x8 a = *(const bf16x8*)(&h_lds[p][0][0] + r * 264 + kc * 32 + q * 8);
            #pragma unroll
            for (int tt = 0; tt < 8; ++tt) acc[tt] = mfma16(a, u_res[kc][tt], acc[tt]);
        }
        #pragma unroll
        for (int kc = 3; kc < 8; ++kc) {
            bf16x8 a = *(const bf16x8*)(&h_lds[p][0][0] + r * 264 + kc * 32 + q * 8);
            #pragma unroll
            for (int tt = 0; tt < 8; ++tt) {
                bf16x8 u = *(const bf16x8*)(Upk + (size_t)(((w * 8 + kc) * 8 + tt) * 64 + l) * 8);
                acc[tt] = mfma16(a, u, acc[tt]);
            }
        }
        // LSTM cell: wave owns k-slice [32w,32w+32) -> i/f/g/o in its own accumulators
        float ypj[4] = {0.f, 0.f, 0.f, 0.f};
        #pragma unroll
        for (int sub = 0; sub < 2; ++sub) {
            #pragma unroll
            for (int j = 0; j < 4; ++j) {
                float iv = sigm(acc[0 + sub][j] + gxel(gx[0 + sub], j));
                float fv = sigm(acc[2 + sub][j] + gxel(gx[2 + sub], j));
                float gv = tanh_f(acc[4 + sub][j] + gxel(gx[4 + sub], j));
                float ov = sigm(acc[6 + sub][j] + gxel(gx[6 + sub], j));
                float c = fv * c_st[sub][j] + iv * gv;
                c_st[sub][j] = c;
                float hv = ov * tanh_f(c);
                int row = q * 4 + j, k = w * 32 + sub * 16 + r;
                h_lds[np][row][k] = f2bf(hv);
                outh[((size_t)(g * 16 + row) * 128 + t) * 256 + k] = hv;
                ypj[j] += hv * fw[sub];
            }
        }
        #pragma unroll
        for (int j = 0; j < 4; ++j) {   // reduce y partial over the 16-lane group
            float v = ypj[j];
            v += __shfl_xor(v, 1);
            v += __shfl_xor(v, 2);
            v += __shfl_xor(v, 4);
            v += __shfl_xor(v, 8);
            if (r == 0) ypart[np][w][q * 4 + j] = v;
        }
        __syncthreads();
    }
    if (tid < 16) {
        float y = fc_b0;
        #pragma unroll
        for (int ww = 0; ww < 8; ++ww) y += ypart[0][ww][tid];
        out[g * 16 + tid] = y;
    }
}

extern "C" void kernel_launch(void* const* d_in, const int* in_sizes, int n_in,
                              void* d_out, int out_size, void* d_ws, size_t ws_size,
                              hipStream_t stream) {
    const float* H    = (const float*)d_in[0];
    const float* y0   = (const float*)d_in[1];
    const float* Wa   = (const float*)d_in[2];
    // d_in[3] = Ua: multiplied by an all-zero state in the reference -> unused
    const float* ba   = (const float*)d_in[4];
    const float* Va   = (const float*)d_in[5];
    const float* W    = (const float*)d_in[6];
    const float* U    = (const float*)d_in[7];
    const float* bias = (const float*)d_in[8];
    const float* Wy   = (const float*)d_in[9];
    const float* fcW  = (const float*)d_in[10];
    const float* fcb  = (const float*)d_in[11];
    float* out = (float*)d_out;
    char* ws = (char*)d_ws;

    unsigned short* Hbf   = (unsigned short*)(ws);
    unsigned short* HT    = (unsigned short*)(ws + 16777216);
    unsigned short* T1    = (unsigned short*)(ws + 2 * 16777216);
    unsigned short* beta  = (unsigned short*)(ws + 3 * 16777216);
    unsigned short* poolT = (unsigned short*)(ws + 4 * 16777216);
    unsigned short* Gxp   = (unsigned short*)(ws + (size_t)5 * 16777216);        // 134.2 MB
    unsigned short* WaT   = (unsigned short*)(ws + (size_t)5 * 16777216 + 134217728);
    unsigned short* VaT   = WaT + 16384;
    unsigned short* WT    = VaT + 16384;
    unsigned short* Upk   = WT + 131072;

    hipLaunchKernelGGL(k_prepw, dim3(1664), dim3(256), 0, stream, Wa, Va, W, U, WaT, VaT, WT, Upk);
    hipLaunchKernelGGL(k_preph, dim3(8192), dim3(256), 0, stream, H, Hbf, HT);
    hipLaunchKernelGGL(k_att1, dim3(1024), dim3(256), 0, stream, Hbf, WaT, ba, T1);
    hipLaunchKernelGGL(k_att2, dim3(1024), dim3(256), 0, stream, T1, VaT, beta);
    hipLaunchKernelGGL(k_pool, dim3(1024), dim3(256), 0, stream, beta, HT, poolT);
    hipLaunchKernelGGL(k_gx, dim3(8192), dim3(256), 0, stream, poolT, WT, bias, Gxp);
    hipLaunchKernelGGL(k_seq, dim3(32), dim3(512), 0, stream, Gxp, Upk, Wy, fcW, fcb, y0, out);
}

// Round 2
// 1193.071 us; speedup vs baseline: 1.4907x; 1.4907x over previous
//
#include <hip/hip_runtime.h>
#include <hip/hip_bf16.h>

// Shapes: B=512, S=128, D=128, HS=256, 4HS=1024, O=1.
// Pipeline (all bf16 MFMA, f32 accum):
//   prepw: WaT/VaT/WT transposed bf16 weights + U packed into MFMA B-fragment order
//   preph: H -> bf16 copy + per-b transpose HT[b][d][s]
//   k_att1: T1 = tanh(H @ Wa + ba)
//   k_att2: beta = softmax(T1 @ Va)
//   k_pool: poolT[t*512+b][d] = beta[b] @ H[b]
//   k_gx:   Gx = pool @ W + bias, packed [g][t][w][gate][lane][8] bf16 (16B/lane)
//   k_seq:  32 blocks x 16 batch rows, 128-step LSTM.
//           U residency: kc0-2 in VGPRs (96), kc3-4 in LDS (128KB, loaded once),
//           kc5-7 streamed from L2 with rotating prefetch buffer.
//           h double-buffer kept in LDS in exact MFMA-A-fragment order -> conflict-free b128.

using bf16x8 = __attribute__((ext_vector_type(8))) short;
using f32x4  = __attribute__((ext_vector_type(4))) float;

#define DEV static __device__ __forceinline__

DEV unsigned short f2bf(float x) {
    unsigned u = __float_as_uint(x);
    u += 0x7fffu + ((u >> 16) & 1u);          // round-to-nearest-even
    return (unsigned short)(u >> 16);
}
DEV float bf2f(unsigned short s) { return __uint_as_float(((unsigned)s) << 16); }
DEV float sigm(float x) { return 1.0f / (1.0f + __expf(-x)); }
DEV float tanh_f(float x) { float e = __expf(2.0f * x); return 1.0f - 2.0f / (e + 1.0f); }
DEV f32x4 mfma16(bf16x8 a, bf16x8 b, f32x4 c) {
    return __builtin_amdgcn_mfma_f32_16x16x32_bf16(a, b, c, 0, 0, 0);
}

// stage rows x 128 bf16 (row stride 128) into LDS with padded stride 136
DEV void stage128(const unsigned short* __restrict__ src, unsigned short* dst, int rows, int tid) {
    int chunks = rows * 16;
    for (int i = tid; i < chunks; i += 256) {
        int r = i >> 4, c = (i & 15) << 3;
        *(bf16x8*)(dst + r * 136 + c) = *(const bf16x8*)(src + r * 128 + c);
    }
}

// ---------------- prep kernels ----------------
__global__ void k_prepw(const float* __restrict__ Wa, const float* __restrict__ Va,
                        const float* __restrict__ W, const float* __restrict__ U,
                        unsigned short* __restrict__ WaT, unsigned short* __restrict__ VaT,
                        unsigned short* __restrict__ WT, unsigned short* __restrict__ Upk) {
    int idx = blockIdx.x * 256 + threadIdx.x;
    if (idx < 16384) {
        int n = idx >> 7, k = idx & 127;
        WaT[idx] = f2bf(Wa[k * 128 + n]);
    } else if (idx < 32768) {
        int i = idx - 16384;
        int n = i >> 7, k = i & 127;
        VaT[i] = f2bf(Va[k * 128 + n]);
    } else if (idx < 163840) {
        int i = idx - 32768;
        int n = i >> 7, k = i & 127;
        WT[i] = f2bf(W[k * 1024 + n]);
    } else if (idx < 425984) {
        int i = idx - 163840;   // layout: ((((w*8+kc)*8+tt)*64+l)*8+j
        int j = i & 7, ll = (i >> 3) & 63, tt = (i >> 9) & 7, kc = (i >> 12) & 7, w = i >> 15;
        int k = kc * 32 + (ll >> 4) * 8 + j;
        int n = (tt >> 1) * 256 + w * 32 + (tt & 1) * 16 + (ll & 15);
        Upk[i] = f2bf(U[k * 1024 + n]);
    }
}

__global__ void k_preph(const float* __restrict__ H, unsigned short* __restrict__ Hbf,
                        unsigned short* __restrict__ HT) {
    for (size_t idx = (size_t)blockIdx.x * 256 + threadIdx.x; idx < 16777216u;
         idx += (size_t)gridDim.x * 256) {
        if (idx < 8388608u) {
            Hbf[idx] = f2bf(H[idx]);
        } else {
            size_t i = idx - 8388608u;
            int b = (int)(i >> 14);
            int rem = (int)(i & 16383);
            int d = rem >> 7, s = rem & 127;
            HT[i] = f2bf(H[((size_t)b * 128 + s) * 128 + d]);
        }
    }
}

// ---------------- T1 = tanh(H @ Wa + ba) ----------------
__global__ __launch_bounds__(256) void k_att1(const unsigned short* __restrict__ Hbf,
                                              const unsigned short* __restrict__ WaT,
                                              const float* __restrict__ ba,
                                              unsigned short* __restrict__ T1) {
    __shared__ unsigned short a_lds[64 * 136];
    __shared__ unsigned short b_lds[128 * 136];
    int tid = threadIdx.x;
    int m0 = blockIdx.x * 64;
    stage128(Hbf + (size_t)m0 * 128, a_lds, 64, tid);
    stage128(WaT, b_lds, 128, tid);
    __syncthreads();
    int w = tid >> 6, l = tid & 63, q = l >> 4, r = l & 15;
    f32x4 acc[8] = {};
    #pragma unroll
    for (int kc = 0; kc < 4; ++kc) {
        bf16x8 a = *(const bf16x8*)(a_lds + (w * 16 + r) * 136 + kc * 32 + q * 8);
        #pragma unroll
        for (int nt = 0; nt < 8; ++nt) {
            bf16x8 b = *(const bf16x8*)(b_lds + (nt * 16 + r) * 136 + kc * 32 + q * 8);
            acc[nt] = mfma16(a, b, acc[nt]);
        }
    }
    #pragma unroll
    for (int nt = 0; nt < 8; ++nt) {
        int col = nt * 16 + r;
        float bav = ba[col];
        #pragma unroll
        for (int j = 0; j < 4; ++j) {
            int row = m0 + w * 16 + q * 4 + j;
            T1[(size_t)row * 128 + col] = f2bf(tanh_f(acc[nt][j] + bav));
        }
    }
}

// ---------------- beta = softmax(T1 @ Va) ----------------
__global__ __launch_bounds__(256) void k_att2(const unsigned short* __restrict__ T1,
                                              const unsigned short* __restrict__ VaT,
                                              unsigned short* __restrict__ beta) {
    __shared__ __align__(16) char smem[52224];
    unsigned short* a_lds = (unsigned short*)smem;
    unsigned short* b_lds = (unsigned short*)(smem + 17408);
    float* lg  = (float*)smem;
    float* inv = (float*)(smem + 34048);
    int tid = threadIdx.x;
    int m0 = blockIdx.x * 64;
    stage128(T1 + (size_t)m0 * 128, a_lds, 64, tid);
    stage128(VaT, b_lds, 128, tid);
    __syncthreads();
    int w = tid >> 6, l = tid & 63, q = l >> 4, r = l & 15;
    f32x4 acc[8] = {};
    #pragma unroll
    for (int kc = 0; kc < 4; ++kc) {
        bf16x8 a = *(const bf16x8*)(a_lds + (w * 16 + r) * 136 + kc * 32 + q * 8);
        #pragma unroll
        for (int nt = 0; nt < 8; ++nt) {
            bf16x8 b = *(const bf16x8*)(b_lds + (nt * 16 + r) * 136 + kc * 32 + q * 8);
            acc[nt] = mfma16(a, b, acc[nt]);
        }
    }
    __syncthreads();
    #pragma unroll
    for (int nt = 0; nt < 8; ++nt)
        #pragma unroll
        for (int j = 0; j < 4; ++j)
            lg[(w * 16 + q * 4 + j) * 133 + nt * 16 + r] = acc[nt][j];
    __syncthreads();
    if (tid < 64) {
        float mx = -1e30f;
        for (int c = 0; c < 128; ++c) mx = fmaxf(mx, lg[tid * 133 + c]);
        float s = 0.f;
        for (int c = 0; c < 128; ++c) {
            float e = __expf(lg[tid * 133 + c] - mx);
            lg[tid * 133 + c] = e;
            s += e;
        }
        inv[tid] = 1.0f / s;
    }
    __syncthreads();
    for (int i = tid; i < 64 * 128; i += 256) {
        int rr = i >> 7, cc = i & 127;
        beta[(size_t)(m0 + rr) * 128 + cc] = f2bf(lg[rr * 133 + cc] * inv[rr]);
    }
}

// ---------------- poolT[t*512+b][d] = beta[b] @ H[b] ----------------
__global__ __launch_bounds__(256) void k_pool(const unsigned short* __restrict__ beta,
                                              const unsigned short* __restrict__ HT,
                                              unsigned short* __restrict__ poolT) {
    __shared__ unsigned short a_lds[64 * 136];
    __shared__ unsigned short b_lds[128 * 136];
    int tid = threadIdx.x;
    int b = blockIdx.x >> 1, mh = blockIdx.x & 1;
    stage128(beta + ((size_t)b * 128 + mh * 64) * 128, a_lds, 64, tid);
    stage128(HT + (size_t)b * 16384, b_lds, 128, tid);
    __syncthreads();
    int w = tid >> 6, l = tid & 63, q = l >> 4, r = l & 15;
    f32x4 acc[8] = {};
    #pragma unroll
    for (int kc = 0; kc < 4; ++kc) {
        bf16x8 a = *(const bf16x8*)(a_lds + (w * 16 + r) * 136 + kc * 32 + q * 8);
        #pragma unroll
        for (int nt = 0; nt < 8; ++nt) {
            bf16x8 bb = *(const bf16x8*)(b_lds + (nt * 16 + r) * 136 + kc * 32 + q * 8);
            acc[nt] = mfma16(a, bb, acc[nt]);
        }
    }
    #pragma unroll
    for (int nt = 0; nt < 8; ++nt)
        #pragma unroll
        for (int j = 0; j < 4; ++j) {
            int t = mh * 64 + w * 16 + q * 4 + j;
            poolT[((size_t)t * 512 + b) * 128 + nt * 16 + r] = f2bf(acc[nt][j]);
        }
}

// ---------------- Gx = pool @ W + bias, packed [g][t][w][gate][lane][8] ----------------
__global__ __launch_bounds__(256) void k_gx(const unsigned short* __restrict__ poolT,
                                            const unsigned short* __restrict__ WT,
                                            const float* __restrict__ bias,
                                            unsigned short* __restrict__ Gxp) {
    __shared__ unsigned short a_lds[64 * 136];
    __shared__ unsigned short b_lds[128 * 136];
    int tid = threadIdx.x;
    int mblk = blockIdx.x >> 3, nb = blockIdx.x & 7;
    int t = mblk >> 3, gblk = mblk & 7;
    int m0 = mblk * 64, n0 = nb * 128;
    stage128(poolT + (size_t)m0 * 128, a_lds, 64, tid);
    stage128(WT + (size_t)n0 * 128, b_lds, 128, tid);
    __syncthreads();
    int w = tid >> 6, l = tid & 63, q = l >> 4, r = l & 15;
    f32x4 acc[8] = {};
    #pragma unroll
    for (int kc = 0; kc < 4; ++kc) {
        bf16x8 a = *(const bf16x8*)(a_lds + (w * 16 + r) * 136 + kc * 32 + q * 8);
        #pragma unroll
        for (int nt = 0; nt < 8; ++nt) {
            bf16x8 bb = *(const bf16x8*)(b_lds + (nt * 16 + r) * 136 + kc * 32 + q * 8);
            acc[nt] = mfma16(a, bb, acc[nt]);
        }
    }
    int g_seq = gblk * 4 + w;   // wave's 16 rows = one sequential batch group
    #pragma unroll
    for (int np2 = 0; np2 < 4; ++np2) {
        int nt0 = np2 * 2, nt1 = nt0 + 1;
        int col0 = n0 + nt0 * 16, col1 = n0 + nt1 * 16;
        float bv0 = bias[col0 + r], bv1 = bias[col1 + r];
        int w_seq = (col0 & 255) >> 5;
        int gate = col0 >> 8;
        size_t idx8 = ((((size_t)g_seq * 128 + t) * 8 + w_seq) * 4 + gate) * 64 + l;
        bf16x8 o;
        o[0] = (short)f2bf(acc[nt0][0] + bv0);
        o[1] = (short)f2bf(acc[nt0][1] + bv0);
        o[2] = (short)f2bf(acc[nt0][2] + bv0);
        o[3] = (short)f2bf(acc[nt0][3] + bv0);
        o[4] = (short)f2bf(acc[nt1][0] + bv1);
        o[5] = (short)f2bf(acc[nt1][1] + bv1);
        o[6] = (short)f2bf(acc[nt1][2] + bv1);
        o[7] = (short)f2bf(acc[nt1][3] + bv1);
        *(bf16x8*)(Gxp + idx8 * 8) = o;   // 16B/lane, lane-contiguous
    }
}

// ---------------- sequential LSTM: 32 blocks x 16 batch rows ----------------
// dynamic LDS: U kc3-4 (131072 B) | h frag-order dbuf (16384 B) | ypart (1024 B)
__global__ __launch_bounds__(512, 2) void k_seq(const unsigned short* __restrict__ Gxp,
                                                const unsigned short* __restrict__ Upk,
                                                const float* __restrict__ Wy,
                                                const float* __restrict__ fcW,
                                                const float* __restrict__ fcb,
                                                const float* __restrict__ y0,
                                                float* __restrict__ out) {
    extern __shared__ __align__(16) char dynbuf[];
    unsigned short* u2   = (unsigned short*)dynbuf;             // 65536 shorts
    unsigned short* h_fl = (unsigned short*)(dynbuf + 131072);  // 2 x 4096 shorts
    float* ypart         = (float*)(dynbuf + 147456);           // [2][8][16]

    int tid = threadIdx.x;
    int g = blockIdx.x;
    int w = tid >> 6, l = tid & 63, q = l >> 4, r = l & 15;
    float fc_b0 = fcb[0];

    // register-resident U: kc 0..2 (96 VGPRs)
    bf16x8 u_res[3][8];
    #pragma unroll
    for (int kc = 0; kc < 3; ++kc)
        #pragma unroll
        for (int tt = 0; tt < 8; ++tt)
            u_res[kc][tt] = *(const bf16x8*)(Upk + (size_t)(((w * 8 + kc) * 8 + tt) * 64 + l) * 8);

    // LDS-resident U: kc 3..4 (each lane copies its own fragment -> conflict-free b128)
    #pragma unroll
    for (int kcL = 0; kcL < 2; ++kcL)
        #pragma unroll
        for (int tt = 0; tt < 8; ++tt) {
            size_t gofs = (size_t)(((w * 8 + 3 + kcL) * 8 + tt) * 64 + l) * 8;
            size_t lofs = (size_t)(((w * 2 + kcL) * 8 + tt) * 64 + l) * 8;
            *(bf16x8*)(u2 + lofs) = *(const bf16x8*)(Upk + gofs);
        }

    float wy_r[8], fw[2];
    #pragma unroll
    for (int tt = 0; tt < 8; ++tt)
        wy_r[tt] = Wy[(tt >> 1) * 256 + w * 32 + (tt & 1) * 16 + r];
    fw[0] = fcW[w * 32 + r];
    fw[1] = fcW[w * 32 + 16 + r];
    float c_st[2][4] = {};

    for (int i = tid; i < 4096; i += 512) h_fl[i] = 0;   // h(0) = 0, frag-order buf 0
    if (tid < 128) {
        int ww = tid >> 4, rw = tid & 15;
        ypart[ww * 16 + rw] = (ww == 0) ? (y0[g * 16 + rw] - fc_b0) : 0.0f;
        ypart[128 + ww * 16 + rw] = 0.0f;
    }
    __syncthreads();

    float* outh = out + 512;
    for (int t = 0; t < 128; ++t) {
        int p = t & 1, np = p ^ 1;
        unsigned short* hp = h_fl + p * 4096;
        unsigned short* hn = h_fl + np * 4096;
        float* ypp = ypart + p * 128;
        float* ypn = ypart + np * 128;

        // ---- prefetches issued first: Gx (4x dwordx4) + streamed U kc5 ----
        bf16x8 gxq[4];
        {
            size_t base = ((((size_t)g * 128 + t) * 8 + w) * 4) * 64 + l;
            const bf16x8* gq = (const bf16x8*)Gxp;
            #pragma unroll
            for (int gate = 0; gate < 4; ++gate) gxq[gate] = gq[base + (size_t)gate * 64];
        }
        bf16x8 ubN[8];
        #pragma unroll
        for (int tt = 0; tt < 8; ++tt)
            ubN[tt] = *(const bf16x8*)(Upk + (size_t)(((w * 8 + 5) * 8 + tt) * 64 + l) * 8);

        // ---- y_prev assembly + acc init with Wy outer product ----
        float yp[4];
        #pragma unroll
        for (int j = 0; j < 4; ++j) {
            float s = fc_b0;
            #pragma unroll
            for (int ww = 0; ww < 8; ++ww) s += ypp[ww * 16 + q * 4 + j];
            yp[j] = s;
        }
        f32x4 acc[8];
        #pragma unroll
        for (int tt = 0; tt < 8; ++tt) {
            acc[tt][0] = yp[0] * wy_r[tt];
            acc[tt][1] = yp[1] * wy_r[tt];
            acc[tt][2] = yp[2] * wy_r[tt];
            acc[tt][3] = yp[3] * wy_r[tt];
        }

        // ---- register kcs 0..2 ----
        #pragma unroll
        for (int kc = 0; kc < 3; ++kc) {
            bf16x8 a = *(const bf16x8*)(hp + ((kc * 4 + q) * 16 + r) * 8);
            #pragma unroll
            for (int tt = 0; tt < 8; ++tt) acc[tt] = mfma16(a, u_res[kc][tt], acc[tt]);
        }
        // ---- LDS kcs 3..4 ----
        #pragma unroll
        for (int kcL = 0; kcL < 2; ++kcL) {
            bf16x8 a = *(const bf16x8*)(hp + (((3 + kcL) * 4 + q) * 16 + r) * 8);
            #pragma unroll
            for (int tt = 0; tt < 8; ++tt) {
                bf16x8 u = *(const bf16x8*)(u2 + (size_t)(((w * 2 + kcL) * 8 + tt) * 64 + l) * 8);
                acc[tt] = mfma16(a, u, acc[tt]);
            }
        }
        // ---- streamed kcs 5..7, software-pipelined rotating buffer ----
        #pragma unroll
        for (int kc = 5; kc < 8; ++kc) {
            bf16x8 uc[8];
            #pragma unroll
            for (int tt = 0; tt < 8; ++tt) uc[tt] = ubN[tt];
            if (kc < 7) {
                #pragma unroll
                for (int tt = 0; tt < 8; ++tt)
                    ubN[tt] = *(const bf16x8*)(Upk + (size_t)(((w * 8 + kc + 1) * 8 + tt) * 64 + l) * 8);
            }
            bf16x8 a = *(const bf16x8*)(hp + ((kc * 4 + q) * 16 + r) * 8);
            #pragma unroll
            for (int tt = 0; tt < 8; ++tt) acc[tt] = mfma16(a, uc[tt], acc[tt]);
        }

        // ---- LSTM cell ----
        float ypj[4] = {0.f, 0.f, 0.f, 0.f};
        #pragma unroll
        for (int sub = 0; sub < 2; ++sub) {
            #pragma unroll
            for (int j = 0; j < 4; ++j) {
                float iv = sigm(acc[0 + sub][j] + bf2f((unsigned short)gxq[0][sub * 4 + j]));
                float fv = sigm(acc[2 + sub][j] + bf2f((unsigned short)gxq[1][sub * 4 + j]));
                float gv = tanh_f(acc[4 + sub][j] + bf2f((unsigned short)gxq[2][sub * 4 + j]));
                float ov = sigm(acc[6 + sub][j] + bf2f((unsigned short)gxq[3][sub * 4 + j]));
                float c = fv * c_st[sub][j] + iv * gv;
                c_st[sub][j] = c;
                float hv = ov * tanh_f(c);
                int row = q * 4 + j, k = w * 32 + sub * 16 + r;
                // h write in A-fragment order: kc=w, qd=sub*2+(r>>3), elem=r&7
                hn[((w * 4 + sub * 2 + (r >> 3)) * 16 + row) * 8 + (r & 7)] = f2bf(hv);
                outh[((size_t)(g * 16 + row) * 128 + t) * 256 + k] = hv;
                ypj[j] += hv * fw[sub];
            }
        }
        #pragma unroll
        for (int j = 0; j < 4; ++j) {   // reduce y partial over the 16-lane group
            float v = ypj[j];
            v += __shfl_xor(v, 1);
            v += __shfl_xor(v, 2);
            v += __shfl_xor(v, 4);
            v += __shfl_xor(v, 8);
            if (r == 0) ypn[w * 16 + q * 4 + j] = v;
        }
        __syncthreads();
    }
    if (tid < 16) {
        float y = fc_b0;
        #pragma unroll
        for (int ww = 0; ww < 8; ++ww) y += ypart[ww * 16 + tid];
        out[g * 16 + tid] = y;
    }
}

extern "C" void kernel_launch(void* const* d_in, const int* in_sizes, int n_in,
                              void* d_out, int out_size, void* d_ws, size_t ws_size,
                              hipStream_t stream) {
    const float* H    = (const float*)d_in[0];
    const float* y0   = (const float*)d_in[1];
    const float* Wa   = (const float*)d_in[2];
    // d_in[3] = Ua: multiplied by an all-zero state in the reference -> unused
    const float* ba   = (const float*)d_in[4];
    const float* Va   = (const float*)d_in[5];
    const float* W    = (const float*)d_in[6];
    const float* U    = (const float*)d_in[7];
    const float* bias = (const float*)d_in[8];
    const float* Wy   = (const float*)d_in[9];
    const float* fcW  = (const float*)d_in[10];
    const float* fcb  = (const float*)d_in[11];
    float* out = (float*)d_out;
    char* ws = (char*)d_ws;

    unsigned short* Hbf   = (unsigned short*)(ws);
    unsigned short* HT    = (unsigned short*)(ws + 16777216);
    unsigned short* T1    = (unsigned short*)(ws + 2 * 16777216);
    unsigned short* beta  = (unsigned short*)(ws + 3 * 16777216);
    unsigned short* poolT = (unsigned short*)(ws + 4 * 16777216);
    unsigned short* Gxp   = (unsigned short*)(ws + (size_t)5 * 16777216);        // 134.2 MB
    unsigned short* WaT   = (unsigned short*)(ws + (size_t)5 * 16777216 + 134217728);
    unsigned short* VaT   = WaT + 16384;
    unsigned short* WT    = VaT + 16384;
    unsigned short* Upk   = WT + 131072;

    static int attr_set = 0;   // idempotent; same call every launch (graph-safe, not a stream op)
    hipFuncSetAttribute((const void*)k_seq, hipFuncAttributeMaxDynamicSharedMemorySize, 148480);
    (void)attr_set;

    hipLaunchKernelGGL(k_prepw, dim3(1664), dim3(256), 0, stream, Wa, Va, W, U, WaT, VaT, WT, Upk);
    hipLaunchKernelGGL(k_preph, dim3(8192), dim3(256), 0, stream, H, Hbf, HT);
    hipLaunchKernelGGL(k_att1, dim3(1024), dim3(256), 0, stream, Hbf, WaT, ba, T1);
    hipLaunchKernelGGL(k_att2, dim3(1024), dim3(256), 0, stream, T1, VaT, beta);
    hipLaunchKernelGGL(k_pool, dim3(1024), dim3(256), 0, stream, beta, HT, poolT);
    hipLaunchKernelGGL(k_gx, dim3(8192), dim3(256), 0, stream, poolT, WT, bias, Gxp);
    hipLaunchKernelGGL(k_seq, dim3(32), dim3(512), 148480, stream, Gxp, Upk, Wy, fcW, fcb, y0, out);
}